// Round 1
// baseline (1672.906 us; speedup 1.0000x reference)
//
#include <hip/hip_runtime.h>

typedef short short8 __attribute__((ext_vector_type(8)));
typedef __bf16 bf16x8 __attribute__((ext_vector_type(8)));
typedef float f32x4 __attribute__((ext_vector_type(4)));

#define FEAT 128
#define FPL 2048

__device__ __forceinline__ float b2f(unsigned int u) {
  union { unsigned int u; float f; } c; c.u = u << 16; return c.f;
}
__device__ __forceinline__ unsigned short f2b(float f) {
  union { float f; unsigned int u; } c; c.f = f;
  unsigned int r = c.u + 0x7fffu + ((c.u >> 16) & 1u);
  return (unsigned short)(r >> 16);
}
__device__ __forceinline__ f32x4 mfma16(short8 a, short8 b, f32x4 c) {
  return __builtin_amdgcn_mfma_f32_16x16x32_bf16(
      __builtin_bit_cast(bf16x8, a), __builtin_bit_cast(bf16x8, b), c, 0, 0, 0);
}

// ---- conversion kernels ----
__global__ void cvt_kernel(const float* __restrict__ in, unsigned short* __restrict__ out, int n2) {
  int i = blockIdx.x * 256 + threadIdx.x;
  if (i < n2) {
    float2 v = ((const float2*)in)[i];
    unsigned int lo = f2b(v.x), hi = f2b(v.y);
    ((unsigned int*)out)[i] = lo | (hi << 16);
  }
}

// W[K][N] (row-major) -> WT[N][K] bf16
__global__ void cvtT_kernel(const float* __restrict__ W, unsigned short* __restrict__ WT, int K, int N) {
  int i = blockIdx.x * 256 + threadIdx.x;
  if (i < K * N) {
    int k = i / N, c = i - k * N;
    WT[(size_t)c * K + k] = f2b(W[i]);
  }
}

// ---- CSR build ----
__global__ void count_kernel(const int* __restrict__ dst, int* __restrict__ cnt, int n) {
  int i = blockIdx.x * 256 + threadIdx.x;
  if (i < n) atomicAdd(&cnt[dst[i]], 1);
}

__global__ __launch_bounds__(1024) void scan_kernel(const int* __restrict__ cnt, int* __restrict__ rp, int n) {
  __shared__ int sd[1024];
  __shared__ int carry;
  if (threadIdx.x == 0) carry = 0;
  __syncthreads();
  for (int base = 0; base < n; base += 1024) {
    int i = base + (int)threadIdx.x;
    int v = (i < n) ? cnt[i] : 0;
    sd[threadIdx.x] = v;
    __syncthreads();
    int sum = v;
    for (int off = 1; off < 1024; off <<= 1) {
      int t = (threadIdx.x >= (unsigned)off) ? sd[threadIdx.x - off] : 0;
      __syncthreads();
      sum += t;
      sd[threadIdx.x] = sum;
      __syncthreads();
    }
    if (i < n) rp[i] = carry + sum - v;  // exclusive
    __syncthreads();
    if (threadIdx.x == 1023) carry += sum;
    __syncthreads();
  }
  if (threadIdx.x == 0) rp[n] = carry;
}

__global__ void copy_kernel(const int* __restrict__ a, int* __restrict__ b, int n) {
  int i = blockIdx.x * 256 + threadIdx.x;
  if (i < n) b[i] = a[i];
}

__global__ void fill_kernel(const int* __restrict__ src, const int* __restrict__ dst,
                            int* __restrict__ cursor, int* __restrict__ col, int n) {
  int i = blockIdx.x * 256 + threadIdx.x;
  if (i < n) {
    int p = atomicAdd(&cursor[dst[i]], 1);
    col[p] = src[i];
  }
}

// ---- neighbor gather: agg[i] = x[i] + sum_{j in N(i)} x[j], bf16 in/out, fp32 accum ----
__global__ __launch_bounds__(256) void gather_kernel(const unsigned short* __restrict__ x,
    const int* __restrict__ rp, const int* __restrict__ col,
    unsigned short* __restrict__ agg, int n) {
  int wid = (blockIdx.x * 256 + threadIdx.x) >> 6;
  int lane = threadIdx.x & 63;
  if (wid >= n) return;
  const unsigned int* xw = (const unsigned int*)x;
  unsigned int s = xw[(size_t)wid * 64 + lane];
  float ax = b2f(s & 0xffffu), ay = b2f(s >> 16);
  int beg = rp[wid], end = rp[wid + 1];
  int j = beg;
  for (; j + 4 <= end; j += 4) {
    int c0 = col[j], c1 = col[j + 1], c2 = col[j + 2], c3 = col[j + 3];
    unsigned int v0 = xw[(size_t)c0 * 64 + lane];
    unsigned int v1 = xw[(size_t)c1 * 64 + lane];
    unsigned int v2 = xw[(size_t)c2 * 64 + lane];
    unsigned int v3 = xw[(size_t)c3 * 64 + lane];
    ax += b2f(v0 & 0xffffu) + b2f(v1 & 0xffffu) + b2f(v2 & 0xffffu) + b2f(v3 & 0xffffu);
    ay += b2f(v0 >> 16) + b2f(v1 >> 16) + b2f(v2 >> 16) + b2f(v3 >> 16);
  }
  for (; j < end; ++j) {
    unsigned int v = xw[(size_t)col[j] * 64 + lane];
    ax += b2f(v & 0xffffu);
    ay += b2f(v >> 16);
  }
  ((unsigned int*)agg)[(size_t)wid * 64 + lane] = (unsigned int)f2b(ax) | ((unsigned int)f2b(ay) << 16);
}

// ---- GEMM1: H = relu(A @ W1 + b1), [n,128]x[128,128], bf16 in/out ----
// wave handles 16 rows x 128 cols. A==H in-place is safe (wave-exclusive rows).
__global__ __launch_bounds__(256) void gemm1_kernel(
    const unsigned short* __restrict__ A, const unsigned short* __restrict__ W1T,
    const float* __restrict__ b1, unsigned short* __restrict__ H, int n) {
  const int wave = threadIdx.x >> 6;
  const int lane = threadIdx.x & 63;
  const int lr = lane & 15, lg = lane >> 4;
  const int rowBase = blockIdx.x * 64 + wave * 16;
  short8 a[4];
#pragma unroll
  for (int kt = 0; kt < 4; ++kt)
    a[kt] = *(const short8*)(A + (size_t)(rowBase + lr) * FEAT + kt * 32 + lg * 8);
  f32x4 acc[8];
#pragma unroll
  for (int ct = 0; ct < 8; ++ct) {
    const unsigned short* bp = W1T + (size_t)(ct * 16 + lr) * FEAT + lg * 8;
    f32x4 c = {0.f, 0.f, 0.f, 0.f};
    c = mfma16(a[0], *(const short8*)(bp), c);
    c = mfma16(a[1], *(const short8*)(bp + 32), c);
    c = mfma16(a[2], *(const short8*)(bp + 64), c);
    c = mfma16(a[3], *(const short8*)(bp + 96), c);
    acc[ct] = c;
  }
#pragma unroll
  for (int ct = 0; ct < 8; ++ct) {
    const int c = ct * 16 + lr;
    const float bias = b1[c];
#pragma unroll
    for (int j = 0; j < 4; ++j) {
      const int row = rowBase + lg * 4 + j;
      if (row < n) {
        float v = acc[ct][j] + bias;
        H[(size_t)row * FEAT + c] = f2b(v > 0.f ? v : 0.f);
      }
    }
  }
}

// ---- GEMM2 fused: logits = H @ W2 + b2; softmax rows; fp_partial += colsum(probs) ----
// 512 threads = 8 waves; block handles 32 rows; wave w owns cols [256w, 256w+256).
__global__ __launch_bounds__(512) void gemm2_kernel(
    const unsigned short* __restrict__ H, const unsigned short* __restrict__ W2T,
    const float* __restrict__ b2, float* __restrict__ partials, int n, int nBlocks) {
  __shared__ float redM[32][8];
  __shared__ float redS[32][8];
  __shared__ float fp_lds[FPL];
  const int wave = threadIdx.x >> 6;
  const int lane = threadIdx.x & 63;
  const int lr = lane & 15;
  const int lg = lane >> 4;
  for (int i = threadIdx.x; i < FPL; i += 512) fp_lds[i] = 0.f;
  float b2v[16];
#pragma unroll
  for (int ct = 0; ct < 16; ++ct) b2v[ct] = b2[wave * 256 + ct * 16 + lr];
  __syncthreads();

  for (int blk = blockIdx.x; blk < nBlocks; blk += gridDim.x) {
    const int rowBase = blk * 32;
    short8 a[2][4];
#pragma unroll
    for (int rt = 0; rt < 2; ++rt)
#pragma unroll
      for (int kt = 0; kt < 4; ++kt)
        a[rt][kt] = *(const short8*)(H + (size_t)(rowBase + rt * 16 + lr) * FEAT + kt * 32 + lg * 8);

    f32x4 acc[2][16];
#pragma unroll
    for (int ct = 0; ct < 16; ++ct) {
      const unsigned short* bp = W2T + (size_t)(wave * 256 + ct * 16 + lr) * FEAT + lg * 8;
      short8 b0 = *(const short8*)(bp);
      short8 b1v = *(const short8*)(bp + 32);
      short8 b2w = *(const short8*)(bp + 64);
      short8 b3v = *(const short8*)(bp + 96);
      f32x4 c0 = {0.f, 0.f, 0.f, 0.f};
      f32x4 c1 = {0.f, 0.f, 0.f, 0.f};
      c0 = mfma16(a[0][0], b0, c0);
      c1 = mfma16(a[1][0], b0, c1);
      c0 = mfma16(a[0][1], b1v, c0);
      c1 = mfma16(a[1][1], b1v, c1);
      c0 = mfma16(a[0][2], b2w, c0);
      c1 = mfma16(a[1][2], b2w, c1);
      c0 = mfma16(a[0][3], b3v, c0);
      c1 = mfma16(a[1][3], b3v, c1);
#pragma unroll
      for (int j = 0; j < 4; ++j) { c0[j] += b2v[ct]; c1[j] += b2v[ct]; }
      acc[0][ct] = c0;
      acc[1][ct] = c1;
    }

    // per-row max: reduce over this lane's 16 ct values, then across the 16-lane col group
    float rmax[2][4];
#pragma unroll
    for (int rt = 0; rt < 2; ++rt)
#pragma unroll
      for (int j = 0; j < 4; ++j) {
        float m = acc[rt][0][j];
#pragma unroll
        for (int ct = 1; ct < 16; ++ct) m = fmaxf(m, acc[rt][ct][j]);
#pragma unroll
        for (int d = 1; d < 16; d <<= 1) m = fmaxf(m, __shfl_xor(m, d, 64));
        rmax[rt][j] = m;
      }
    __syncthreads();  // protects redM/redS reuse across iterations
    if (lr == 0) {
#pragma unroll
      for (int rt = 0; rt < 2; ++rt)
#pragma unroll
        for (int j = 0; j < 4; ++j) redM[rt * 16 + lg * 4 + j][wave] = rmax[rt][j];
    }
    __syncthreads();
#pragma unroll
    for (int rt = 0; rt < 2; ++rt)
#pragma unroll
      for (int j = 0; j < 4; ++j) {
        const int r = rt * 16 + lg * 4 + j;
        float m = redM[r][0];
#pragma unroll
        for (int w = 1; w < 8; ++w) m = fmaxf(m, redM[r][w]);
        rmax[rt][j] = m;
      }

    // exp + row sums
    float rsum[2][4];
#pragma unroll
    for (int rt = 0; rt < 2; ++rt)
#pragma unroll
      for (int j = 0; j < 4; ++j) {
        const int row = rowBase + rt * 16 + lg * 4 + j;
        const bool valid = row < n;
        float s = 0.f;
#pragma unroll
        for (int ct = 0; ct < 16; ++ct) {
          float e = valid ? __expf(acc[rt][ct][j] - rmax[rt][j]) : 0.f;
          acc[rt][ct][j] = e;
          s += e;
        }
#pragma unroll
        for (int d = 1; d < 16; d <<= 1) s += __shfl_xor(s, d, 64);
        rsum[rt][j] = s;
      }
    if (lr == 0) {
#pragma unroll
      for (int rt = 0; rt < 2; ++rt)
#pragma unroll
        for (int j = 0; j < 4; ++j) redS[rt * 16 + lg * 4 + j][wave] = rsum[rt][j];
    }
    __syncthreads();
    float rz[2][4];
#pragma unroll
    for (int rt = 0; rt < 2; ++rt)
#pragma unroll
      for (int j = 0; j < 4; ++j) {
        const int r = rt * 16 + lg * 4 + j;
        float z = 0.f;
#pragma unroll
        for (int w = 0; w < 8; ++w) z += redS[r][w];
        rz[rt][j] = z > 0.f ? 1.0f / z : 0.f;
      }

    // column sums of probs -> fp_lds
#pragma unroll
    for (int ct = 0; ct < 16; ++ct) {
      float s = 0.f;
#pragma unroll
      for (int rt = 0; rt < 2; ++rt)
#pragma unroll
        for (int j = 0; j < 4; ++j) s += acc[rt][ct][j] * rz[rt][j];
      s += __shfl_xor(s, 16, 64);
      s += __shfl_xor(s, 32, 64);
      if (lg == 0) fp_lds[wave * 256 + ct * 16 + lr] += s;
    }
  }
  __syncthreads();
  for (int i = threadIdx.x; i < FPL; i += 512)
    partials[(size_t)blockIdx.x * FPL + i] += fp_lds[i];
}

__global__ void reduce_kernel(const float* __restrict__ partials, float* __restrict__ out, int nPart) {
  int c = blockIdx.x * 256 + threadIdx.x;
  if (c < FPL) {
    float s = 0.f;
    for (int p = 0; p < nPart; ++p) s += partials[(size_t)p * FPL + c];
    out[c] = s;
  }
}

extern "C" void kernel_launch(void* const* d_in, const int* in_sizes, int n_in,
                              void* d_out, int out_size, void* d_ws, size_t ws_size,
                              hipStream_t stream) {
  const float* atoms = (const float*)d_in[0];
  const float* W1 = (const float*)d_in[1];
  const float* b1 = (const float*)d_in[2];
  const float* W2 = (const float*)d_in[3];
  const float* b2 = (const float*)d_in[4];
  const int* esrc = (const int*)d_in[5];
  const int* edst = (const int*)d_in[6];
  const int nAtoms = in_sizes[0] / FEAT;
  const int nEdges = in_sizes[5];
  if (nAtoms <= 0) return;

  const int g1Blocks = (nAtoms + 63) / 64;
  const int nPad = g1Blocks * 64;
  const int g2RowBlocks = (nAtoms + 31) / 32;
  const int g2Grid = (g2RowBlocks + 1) / 2;

  size_t off = 0;
  auto alloc = [&](size_t bytes) -> void* {
    void* p = (char*)d_ws + off;
    off += (bytes + 255) & ~(size_t)255;
    return p;
  };
  unsigned short* P = (unsigned short*)alloc((size_t)nPad * FEAT * 2);
  unsigned short* Q = (unsigned short*)alloc((size_t)nPad * FEAT * 2);
  unsigned short* W1T = (unsigned short*)alloc((size_t)FEAT * FEAT * 2);
  unsigned short* W2T = (unsigned short*)alloc((size_t)FEAT * FPL * 2);
  int* counts = (int*)alloc((size_t)nAtoms * 4);
  int* cursor = (int*)alloc((size_t)nAtoms * 4);
  int* rp = (int*)alloc(((size_t)nAtoms + 1) * 4);
  int* col = (int*)alloc((size_t)nEdges * 4);
  float* partials = (float*)alloc((size_t)g2Grid * FPL * 4);

  hipMemsetAsync(counts, 0, (size_t)nAtoms * 4, stream);
  hipMemsetAsync(partials, 0, (size_t)g2Grid * FPL * 4, stream);
  hipMemsetAsync(P + (size_t)nAtoms * FEAT, 0, (size_t)(nPad - nAtoms) * FEAT * 2, stream);
  hipMemsetAsync(Q + (size_t)nAtoms * FEAT, 0, (size_t)(nPad - nAtoms) * FEAT * 2, stream);

  const int n2 = in_sizes[0] / 2;
  cvt_kernel<<<(n2 + 255) / 256, 256, 0, stream>>>(atoms, P, n2);
  cvtT_kernel<<<(FEAT * FEAT + 255) / 256, 256, 0, stream>>>(W1, W1T, FEAT, FEAT);
  cvtT_kernel<<<(FEAT * FPL + 255) / 256, 256, 0, stream>>>(W2, W2T, FEAT, FPL);
  count_kernel<<<(nEdges + 255) / 256, 256, 0, stream>>>(edst, counts, nEdges);
  scan_kernel<<<1, 1024, 0, stream>>>(counts, rp, nAtoms);
  copy_kernel<<<(nAtoms + 255) / 256, 256, 0, stream>>>(rp, cursor, nAtoms);
  fill_kernel<<<(nEdges + 255) / 256, 256, 0, stream>>>(esrc, edst, cursor, col, nEdges);

  unsigned short* x = P;
  unsigned short* y = Q;
  for (int step = 0; step < 3; ++step) {
    gather_kernel<<<(nAtoms + 3) / 4, 256, 0, stream>>>(x, rp, col, y, nAtoms);
    gemm1_kernel<<<g1Blocks, 256, 0, stream>>>(y, W1T, b1, y, nAtoms);
    gemm2_kernel<<<g2Grid, 512, 0, stream>>>(y, W2T, b2, partials, nAtoms, g2RowBlocks);
    unsigned short* t = x; x = y; y = t;
  }
  reduce_kernel<<<(FPL + 255) / 256, 256, 0, stream>>>(partials, (float*)d_out, g2Grid);
}

// Round 2
// 1665.716 us; speedup vs baseline: 1.0043x; 1.0043x over previous
//
#include <hip/hip_runtime.h>

typedef short short8 __attribute__((ext_vector_type(8)));
typedef __bf16 bf16x8 __attribute__((ext_vector_type(8)));
typedef float f32x4 __attribute__((ext_vector_type(4)));

#define FEAT 128
#define FPL 2048

__device__ __forceinline__ float b2f(unsigned int u) {
  union { unsigned int u; float f; } c; c.u = u << 16; return c.f;
}
__device__ __forceinline__ unsigned short f2b(float f) {
  union { float f; unsigned int u; } c; c.f = f;
  unsigned int r = c.u + 0x7fffu + ((c.u >> 16) & 1u);
  return (unsigned short)(r >> 16);
}
__device__ __forceinline__ f32x4 mfma16(short8 a, short8 b, f32x4 c) {
  return __builtin_amdgcn_mfma_f32_16x16x32_bf16(
      __builtin_bit_cast(bf16x8, a), __builtin_bit_cast(bf16x8, b), c, 0, 0, 0);
}

// ---- conversion kernels ----
__global__ void cvt_kernel(const float* __restrict__ in, unsigned short* __restrict__ out, int n2) {
  int i = blockIdx.x * 256 + threadIdx.x;
  if (i < n2) {
    float2 v = ((const float2*)in)[i];
    unsigned int lo = f2b(v.x), hi = f2b(v.y);
    ((unsigned int*)out)[i] = lo | (hi << 16);
  }
}

// W[K][N] (row-major) -> WT[N][K] bf16
__global__ void cvtT_kernel(const float* __restrict__ W, unsigned short* __restrict__ WT, int K, int N) {
  int i = blockIdx.x * 256 + threadIdx.x;
  if (i < K * N) {
    int k = i / N, c = i - k * N;
    WT[(size_t)c * K + k] = f2b(W[i]);
  }
}

// ---- CSR build ----
__global__ void count_kernel(const int* __restrict__ dst, int* __restrict__ cnt, int n) {
  int i = blockIdx.x * 256 + threadIdx.x;
  if (i < n) atomicAdd(&cnt[dst[i]], 1);
}

__global__ __launch_bounds__(1024) void scan_kernel(const int* __restrict__ cnt, int* __restrict__ rp, int n) {
  __shared__ int sd[1024];
  __shared__ int carry;
  if (threadIdx.x == 0) carry = 0;
  __syncthreads();
  for (int base = 0; base < n; base += 1024) {
    int i = base + (int)threadIdx.x;
    int v = (i < n) ? cnt[i] : 0;
    sd[threadIdx.x] = v;
    __syncthreads();
    int sum = v;
    for (int off = 1; off < 1024; off <<= 1) {
      int t = (threadIdx.x >= (unsigned)off) ? sd[threadIdx.x - off] : 0;
      __syncthreads();
      sum += t;
      sd[threadIdx.x] = sum;
      __syncthreads();
    }
    if (i < n) rp[i] = carry + sum - v;  // exclusive
    __syncthreads();
    if (threadIdx.x == 1023) carry += sum;
    __syncthreads();
  }
  if (threadIdx.x == 0) rp[n] = carry;
}

__global__ void copy_kernel(const int* __restrict__ a, int* __restrict__ b, int n) {
  int i = blockIdx.x * 256 + threadIdx.x;
  if (i < n) b[i] = a[i];
}

__global__ void fill_kernel(const int* __restrict__ src, const int* __restrict__ dst,
                            int* __restrict__ cursor, int* __restrict__ col, int n) {
  int i = blockIdx.x * 256 + threadIdx.x;
  if (i < n) {
    int p = atomicAdd(&cursor[dst[i]], 1);
    col[p] = src[i];
  }
}

// ---- neighbor gather: agg[i] = x[i] + sum_{j in N(i)} x[j], bf16 in/out, fp32 accum ----
__global__ __launch_bounds__(256) void gather_kernel(const unsigned short* __restrict__ x,
    const int* __restrict__ rp, const int* __restrict__ col,
    unsigned short* __restrict__ agg, int n) {
  int wid = (blockIdx.x * 256 + threadIdx.x) >> 6;
  int lane = threadIdx.x & 63;
  if (wid >= n) return;
  const unsigned int* xw = (const unsigned int*)x;
  unsigned int s = xw[(size_t)wid * 64 + lane];
  float ax = b2f(s & 0xffffu), ay = b2f(s >> 16);
  int beg = rp[wid], end = rp[wid + 1];
  int j = beg;
  for (; j + 4 <= end; j += 4) {
    int c0 = col[j], c1 = col[j + 1], c2 = col[j + 2], c3 = col[j + 3];
    unsigned int v0 = xw[(size_t)c0 * 64 + lane];
    unsigned int v1 = xw[(size_t)c1 * 64 + lane];
    unsigned int v2 = xw[(size_t)c2 * 64 + lane];
    unsigned int v3 = xw[(size_t)c3 * 64 + lane];
    ax += b2f(v0 & 0xffffu) + b2f(v1 & 0xffffu) + b2f(v2 & 0xffffu) + b2f(v3 & 0xffffu);
    ay += b2f(v0 >> 16) + b2f(v1 >> 16) + b2f(v2 >> 16) + b2f(v3 >> 16);
  }
  for (; j < end; ++j) {
    unsigned int v = xw[(size_t)col[j] * 64 + lane];
    ax += b2f(v & 0xffffu);
    ay += b2f(v >> 16);
  }
  ((unsigned int*)agg)[(size_t)wid * 64 + lane] = (unsigned int)f2b(ax) | ((unsigned int)f2b(ay) << 16);
}

// ---- GEMM1: H = relu(A @ W1 + b1), [n,128]x[128,128], bf16 in/out ----
// wave handles 16 rows x 128 cols. A==H in-place is safe (wave-exclusive rows).
__global__ __launch_bounds__(256) void gemm1_kernel(
    const unsigned short* __restrict__ A, const unsigned short* __restrict__ W1T,
    const float* __restrict__ b1, unsigned short* __restrict__ H, int n) {
  const int wave = threadIdx.x >> 6;
  const int lane = threadIdx.x & 63;
  const int lr = lane & 15, lg = lane >> 4;
  const int rowBase = blockIdx.x * 64 + wave * 16;
  short8 a[4];
#pragma unroll
  for (int kt = 0; kt < 4; ++kt)
    a[kt] = *(const short8*)(A + (size_t)(rowBase + lr) * FEAT + kt * 32 + lg * 8);
  f32x4 acc[8];
#pragma unroll
  for (int ct = 0; ct < 8; ++ct) {
    const unsigned short* bp = W1T + (size_t)(ct * 16 + lr) * FEAT + lg * 8;
    f32x4 c = {0.f, 0.f, 0.f, 0.f};
    c = mfma16(a[0], *(const short8*)(bp), c);
    c = mfma16(a[1], *(const short8*)(bp + 32), c);
    c = mfma16(a[2], *(const short8*)(bp + 64), c);
    c = mfma16(a[3], *(const short8*)(bp + 96), c);
    acc[ct] = c;
  }
#pragma unroll
  for (int ct = 0; ct < 8; ++ct) {
    const int c = ct * 16 + lr;
    const float bias = b1[c];
#pragma unroll
    for (int j = 0; j < 4; ++j) {
      const int row = rowBase + lg * 4 + j;
      if (row < n) {
        float v = acc[ct][j] + bias;
        H[(size_t)row * FEAT + c] = f2b(v > 0.f ? v : 0.f);
      }
    }
  }
}

// ---- GEMM2 fused: logits = H @ W2 + b2; softmax rows; fp_partial += colsum(probs) ----
// 512 threads = 8 waves; block handles 32 rows; wave w owns cols [256w, 256w+256).
// __launch_bounds__(512, 2): 2 waves/EU -> 256-VGPR budget; the ~204-reg live set
// (acc[2][16] f32x4 = 128) must NOT spill (round-1 profile: 128-VGPR cap caused
// 416 MB/dispatch of scratch writes).
__global__ __launch_bounds__(512, 2) void gemm2_kernel(
    const unsigned short* __restrict__ H, const unsigned short* __restrict__ W2T,
    const float* __restrict__ b2, float* __restrict__ partials, int n, int nBlocks) {
  __shared__ float redM[32][8];
  __shared__ float redS[32][8];
  __shared__ float fp_lds[FPL];
  const int wave = threadIdx.x >> 6;
  const int lane = threadIdx.x & 63;
  const int lr = lane & 15;
  const int lg = lane >> 4;
  for (int i = threadIdx.x; i < FPL; i += 512) fp_lds[i] = 0.f;
  float b2v[16];
#pragma unroll
  for (int ct = 0; ct < 16; ++ct) b2v[ct] = b2[wave * 256 + ct * 16 + lr];
  __syncthreads();

  for (int blk = blockIdx.x; blk < nBlocks; blk += gridDim.x) {
    const int rowBase = blk * 32;
    short8 a[2][4];
#pragma unroll
    for (int rt = 0; rt < 2; ++rt)
#pragma unroll
      for (int kt = 0; kt < 4; ++kt)
        a[rt][kt] = *(const short8*)(H + (size_t)(rowBase + rt * 16 + lr) * FEAT + kt * 32 + lg * 8);

    f32x4 acc[2][16];
#pragma unroll
    for (int ct = 0; ct < 16; ++ct) {
      const unsigned short* bp = W2T + (size_t)(wave * 256 + ct * 16 + lr) * FEAT + lg * 8;
      short8 b0 = *(const short8*)(bp);
      short8 b1v = *(const short8*)(bp + 32);
      short8 b2w = *(const short8*)(bp + 64);
      short8 b3v = *(const short8*)(bp + 96);
      f32x4 c0 = {0.f, 0.f, 0.f, 0.f};
      f32x4 c1 = {0.f, 0.f, 0.f, 0.f};
      c0 = mfma16(a[0][0], b0, c0);
      c1 = mfma16(a[1][0], b0, c1);
      c0 = mfma16(a[0][1], b1v, c0);
      c1 = mfma16(a[1][1], b1v, c1);
      c0 = mfma16(a[0][2], b2w, c0);
      c1 = mfma16(a[1][2], b2w, c1);
      c0 = mfma16(a[0][3], b3v, c0);
      c1 = mfma16(a[1][3], b3v, c1);
#pragma unroll
      for (int j = 0; j < 4; ++j) { c0[j] += b2v[ct]; c1[j] += b2v[ct]; }
      acc[0][ct] = c0;
      acc[1][ct] = c1;
    }

    // per-row max: reduce over this lane's 16 ct values, then across the 16-lane col group
    float rmax[2][4];
#pragma unroll
    for (int rt = 0; rt < 2; ++rt)
#pragma unroll
      for (int j = 0; j < 4; ++j) {
        float m = acc[rt][0][j];
#pragma unroll
        for (int ct = 1; ct < 16; ++ct) m = fmaxf(m, acc[rt][ct][j]);
#pragma unroll
        for (int d = 1; d < 16; d <<= 1) m = fmaxf(m, __shfl_xor(m, d, 64));
        rmax[rt][j] = m;
      }
    __syncthreads();  // protects redM/redS reuse across iterations
    if (lr == 0) {
#pragma unroll
      for (int rt = 0; rt < 2; ++rt)
#pragma unroll
        for (int j = 0; j < 4; ++j) redM[rt * 16 + lg * 4 + j][wave] = rmax[rt][j];
    }
    __syncthreads();
#pragma unroll
    for (int rt = 0; rt < 2; ++rt)
#pragma unroll
      for (int j = 0; j < 4; ++j) {
        const int r = rt * 16 + lg * 4 + j;
        float m = redM[r][0];
#pragma unroll
        for (int w = 1; w < 8; ++w) m = fmaxf(m, redM[r][w]);
        rmax[rt][j] = m;
      }

    // exp + row sums
    float rsum[2][4];
#pragma unroll
    for (int rt = 0; rt < 2; ++rt)
#pragma unroll
      for (int j = 0; j < 4; ++j) {
        const int row = rowBase + rt * 16 + lg * 4 + j;
        const bool valid = row < n;
        float s = 0.f;
#pragma unroll
        for (int ct = 0; ct < 16; ++ct) {
          float e = valid ? __expf(acc[rt][ct][j] - rmax[rt][j]) : 0.f;
          acc[rt][ct][j] = e;
          s += e;
        }
#pragma unroll
        for (int d = 1; d < 16; d <<= 1) s += __shfl_xor(s, d, 64);
        rsum[rt][j] = s;
      }
    if (lr == 0) {
#pragma unroll
      for (int rt = 0; rt < 2; ++rt)
#pragma unroll
        for (int j = 0; j < 4; ++j) redS[rt * 16 + lg * 4 + j][wave] = rsum[rt][j];
    }
    __syncthreads();
    float rz[2][4];
#pragma unroll
    for (int rt = 0; rt < 2; ++rt)
#pragma unroll
      for (int j = 0; j < 4; ++j) {
        const int r = rt * 16 + lg * 4 + j;
        float z = 0.f;
#pragma unroll
        for (int w = 0; w < 8; ++w) z += redS[r][w];
        rz[rt][j] = z > 0.f ? 1.0f / z : 0.f;
      }

    // column sums of probs -> fp_lds
#pragma unroll
    for (int ct = 0; ct < 16; ++ct) {
      float s = 0.f;
#pragma unroll
      for (int rt = 0; rt < 2; ++rt)
#pragma unroll
        for (int j = 0; j < 4; ++j) s += acc[rt][ct][j] * rz[rt][j];
      s += __shfl_xor(s, 16, 64);
      s += __shfl_xor(s, 32, 64);
      if (lg == 0) fp_lds[wave * 256 + ct * 16 + lr] += s;
    }
  }
  __syncthreads();
  for (int i = threadIdx.x; i < FPL; i += 512)
    partials[(size_t)blockIdx.x * FPL + i] += fp_lds[i];
}

__global__ void reduce_kernel(const float* __restrict__ partials, float* __restrict__ out, int nPart) {
  int c = blockIdx.x * 256 + threadIdx.x;
  if (c < FPL) {
    float s = 0.f;
    for (int p = 0; p < nPart; ++p) s += partials[(size_t)p * FPL + c];
    out[c] = s;
  }
}

extern "C" void kernel_launch(void* const* d_in, const int* in_sizes, int n_in,
                              void* d_out, int out_size, void* d_ws, size_t ws_size,
                              hipStream_t stream) {
  const float* atoms = (const float*)d_in[0];
  const float* W1 = (const float*)d_in[1];
  const float* b1 = (const float*)d_in[2];
  const float* W2 = (const float*)d_in[3];
  const float* b2 = (const float*)d_in[4];
  const int* esrc = (const int*)d_in[5];
  const int* edst = (const int*)d_in[6];
  const int nAtoms = in_sizes[0] / FEAT;
  const int nEdges = in_sizes[5];
  if (nAtoms <= 0) return;

  const int g1Blocks = (nAtoms + 63) / 64;
  const int nPad = g1Blocks * 64;
  const int g2RowBlocks = (nAtoms + 31) / 32;
  const int g2Grid = (g2RowBlocks + 1) / 2;

  size_t off = 0;
  auto alloc = [&](size_t bytes) -> void* {
    void* p = (char*)d_ws + off;
    off += (bytes + 255) & ~(size_t)255;
    return p;
  };
  unsigned short* P = (unsigned short*)alloc((size_t)nPad * FEAT * 2);
  unsigned short* Q = (unsigned short*)alloc((size_t)nPad * FEAT * 2);
  unsigned short* W1T = (unsigned short*)alloc((size_t)FEAT * FEAT * 2);
  unsigned short* W2T = (unsigned short*)alloc((size_t)FEAT * FPL * 2);
  int* counts = (int*)alloc((size_t)nAtoms * 4);
  int* cursor = (int*)alloc((size_t)nAtoms * 4);
  int* rp = (int*)alloc(((size_t)nAtoms + 1) * 4);
  int* col = (int*)alloc((size_t)nEdges * 4);
  float* partials = (float*)alloc((size_t)g2Grid * FPL * 4);

  hipMemsetAsync(counts, 0, (size_t)nAtoms * 4, stream);
  hipMemsetAsync(partials, 0, (size_t)g2Grid * FPL * 4, stream);
  hipMemsetAsync(P + (size_t)nAtoms * FEAT, 0, (size_t)(nPad - nAtoms) * FEAT * 2, stream);
  hipMemsetAsync(Q + (size_t)nAtoms * FEAT, 0, (size_t)(nPad - nAtoms) * FEAT * 2, stream);

  const int n2 = in_sizes[0] / 2;
  cvt_kernel<<<(n2 + 255) / 256, 256, 0, stream>>>(atoms, P, n2);
  cvtT_kernel<<<(FEAT * FEAT + 255) / 256, 256, 0, stream>>>(W1, W1T, FEAT, FEAT);
  cvtT_kernel<<<(FEAT * FPL + 255) / 256, 256, 0, stream>>>(W2, W2T, FEAT, FPL);
  count_kernel<<<(nEdges + 255) / 256, 256, 0, stream>>>(edst, counts, nEdges);
  scan_kernel<<<1, 1024, 0, stream>>>(counts, rp, nAtoms);
  copy_kernel<<<(nAtoms + 255) / 256, 256, 0, stream>>>(rp, cursor, nAtoms);
  fill_kernel<<<(nEdges + 255) / 256, 256, 0, stream>>>(esrc, edst, cursor, col, nEdges);

  unsigned short* x = P;
  unsigned short* y = Q;
  for (int step = 0; step < 3; ++step) {
    gather_kernel<<<(nAtoms + 3) / 4, 256, 0, stream>>>(x, rp, col, y, nAtoms);
    gemm1_kernel<<<g1Blocks, 256, 0, stream>>>(y, W1T, b1, y, nAtoms);
    gemm2_kernel<<<g2Grid, 512, 0, stream>>>(y, W2T, b2, partials, nAtoms, g2RowBlocks);
    unsigned short* t = x; x = y; y = t;
  }
  reduce_kernel<<<(FPL + 255) / 256, 256, 0, stream>>>(partials, (float*)d_out, g2Grid);
}

// Round 3
// 1599.330 us; speedup vs baseline: 1.0460x; 1.0415x over previous
//
#include <hip/hip_runtime.h>

typedef short short8 __attribute__((ext_vector_type(8)));
typedef __bf16 bf16x8 __attribute__((ext_vector_type(8)));
typedef float f32x4 __attribute__((ext_vector_type(4)));

#define FEAT 128
#define FPL 2048

__device__ __forceinline__ float b2f(unsigned int u) {
  union { unsigned int u; float f; } c; c.u = u << 16; return c.f;
}
__device__ __forceinline__ unsigned short f2b(float f) {
  union { float f; unsigned int u; } c; c.f = f;
  unsigned int r = c.u + 0x7fffu + ((c.u >> 16) & 1u);
  return (unsigned short)(r >> 16);
}
__device__ __forceinline__ f32x4 mfma16(short8 a, short8 b, f32x4 c) {
  return __builtin_amdgcn_mfma_f32_16x16x32_bf16(
      __builtin_bit_cast(bf16x8, a), __builtin_bit_cast(bf16x8, b), c, 0, 0, 0);
}

// ---- conversion kernels ----
__global__ void cvt_kernel(const float* __restrict__ in, unsigned short* __restrict__ out, int n2) {
  int i = blockIdx.x * 256 + threadIdx.x;
  if (i < n2) {
    float2 v = ((const float2*)in)[i];
    unsigned int lo = f2b(v.x), hi = f2b(v.y);
    ((unsigned int*)out)[i] = lo | (hi << 16);
  }
}

// W[K][N] (row-major) -> WT[N][K] bf16
__global__ void cvtT_kernel(const float* __restrict__ W, unsigned short* __restrict__ WT, int K, int N) {
  int i = blockIdx.x * 256 + threadIdx.x;
  if (i < K * N) {
    int k = i / N, c = i - k * N;
    WT[(size_t)c * K + k] = f2b(W[i]);
  }
}

// ---- CSR build ----
__global__ void count_kernel(const int* __restrict__ dst, int* __restrict__ cnt, int n) {
  int i = blockIdx.x * 256 + threadIdx.x;
  if (i < n) atomicAdd(&cnt[dst[i]], 1);
}

__global__ __launch_bounds__(1024) void scan_kernel(const int* __restrict__ cnt, int* __restrict__ rp, int n) {
  __shared__ int sd[1024];
  __shared__ int carry;
  if (threadIdx.x == 0) carry = 0;
  __syncthreads();
  for (int base = 0; base < n; base += 1024) {
    int i = base + (int)threadIdx.x;
    int v = (i < n) ? cnt[i] : 0;
    sd[threadIdx.x] = v;
    __syncthreads();
    int sum = v;
    for (int off = 1; off < 1024; off <<= 1) {
      int t = (threadIdx.x >= (unsigned)off) ? sd[threadIdx.x - off] : 0;
      __syncthreads();
      sum += t;
      sd[threadIdx.x] = sum;
      __syncthreads();
    }
    if (i < n) rp[i] = carry + sum - v;  // exclusive
    __syncthreads();
    if (threadIdx.x == 1023) carry += sum;
    __syncthreads();
  }
  if (threadIdx.x == 0) rp[n] = carry;
}

__global__ void copy_kernel(const int* __restrict__ a, int* __restrict__ b, int n) {
  int i = blockIdx.x * 256 + threadIdx.x;
  if (i < n) b[i] = a[i];
}

__global__ void fill_kernel(const int* __restrict__ src, const int* __restrict__ dst,
                            int* __restrict__ cursor, int* __restrict__ col, int n) {
  int i = blockIdx.x * 256 + threadIdx.x;
  if (i < n) {
    int p = atomicAdd(&cursor[dst[i]], 1);
    col[p] = src[i];
  }
}

// ---- neighbor gather: agg[i] = x[i] + sum_{j in N(i)} x[j], bf16 in/out, fp32 accum ----
__global__ __launch_bounds__(256) void gather_kernel(const unsigned short* __restrict__ x,
    const int* __restrict__ rp, const int* __restrict__ col,
    unsigned short* __restrict__ agg, int n) {
  int wid = (blockIdx.x * 256 + threadIdx.x) >> 6;
  int lane = threadIdx.x & 63;
  if (wid >= n) return;
  const unsigned int* xw = (const unsigned int*)x;
  unsigned int s = xw[(size_t)wid * 64 + lane];
  float ax = b2f(s & 0xffffu), ay = b2f(s >> 16);
  int beg = rp[wid], end = rp[wid + 1];
  int j = beg;
  for (; j + 4 <= end; j += 4) {
    int c0 = col[j], c1 = col[j + 1], c2 = col[j + 2], c3 = col[j + 3];
    unsigned int v0 = xw[(size_t)c0 * 64 + lane];
    unsigned int v1 = xw[(size_t)c1 * 64 + lane];
    unsigned int v2 = xw[(size_t)c2 * 64 + lane];
    unsigned int v3 = xw[(size_t)c3 * 64 + lane];
    ax += b2f(v0 & 0xffffu) + b2f(v1 & 0xffffu) + b2f(v2 & 0xffffu) + b2f(v3 & 0xffffu);
    ay += b2f(v0 >> 16) + b2f(v1 >> 16) + b2f(v2 >> 16) + b2f(v3 >> 16);
  }
  for (; j < end; ++j) {
    unsigned int v = xw[(size_t)col[j] * 64 + lane];
    ax += b2f(v & 0xffffu);
    ay += b2f(v >> 16);
  }
  ((unsigned int*)agg)[(size_t)wid * 64 + lane] = (unsigned int)f2b(ax) | ((unsigned int)f2b(ay) << 16);
}

// ---- GEMM1: H = relu(A @ W1 + b1), [n,128]x[128,128], bf16 in/out ----
// wave handles 16 rows x 128 cols. A==H in-place is safe (wave-exclusive rows).
__global__ __launch_bounds__(256) void gemm1_kernel(
    const unsigned short* __restrict__ A, const unsigned short* __restrict__ W1T,
    const float* __restrict__ b1, unsigned short* __restrict__ H, int n) {
  const int wave = threadIdx.x >> 6;
  const int lane = threadIdx.x & 63;
  const int lr = lane & 15, lg = lane >> 4;
  const int rowBase = blockIdx.x * 64 + wave * 16;
  short8 a[4];
#pragma unroll
  for (int kt = 0; kt < 4; ++kt)
    a[kt] = *(const short8*)(A + (size_t)(rowBase + lr) * FEAT + kt * 32 + lg * 8);
  f32x4 acc[8];
#pragma unroll
  for (int ct = 0; ct < 8; ++ct) {
    const unsigned short* bp = W1T + (size_t)(ct * 16 + lr) * FEAT + lg * 8;
    f32x4 c = {0.f, 0.f, 0.f, 0.f};
    c = mfma16(a[0], *(const short8*)(bp), c);
    c = mfma16(a[1], *(const short8*)(bp + 32), c);
    c = mfma16(a[2], *(const short8*)(bp + 64), c);
    c = mfma16(a[3], *(const short8*)(bp + 96), c);
    acc[ct] = c;
  }
#pragma unroll
  for (int ct = 0; ct < 8; ++ct) {
    const int c = ct * 16 + lr;
    const float bias = b1[c];
#pragma unroll
    for (int j = 0; j < 4; ++j) {
      const int row = rowBase + lg * 4 + j;
      if (row < n) {
        float v = acc[ct][j] + bias;
        H[(size_t)row * FEAT + c] = f2b(v > 0.f ? v : 0.f);
      }
    }
  }
}

// ---- GEMM2 fused: logits = H @ W2 + b2; softmax rows; fp_partial += colsum(probs) ----
// 512 threads = 8 waves; block tile = 16 rows x 2048 cols; wave w owns cols
// [256w, 256w+256). 16 rows (not 32): acc[16] f32x4 = 64 VGPR keeps the live set
// under the 128-VGPR cap (round-1/2 profile: 32-row tile spilled 512 B/thread/iter
// -> 862 MB HBM round-trip per dispatch). Bias lives in LDS, not VGPRs.
__global__ __launch_bounds__(512) void gemm2_kernel(
    const unsigned short* __restrict__ H, const unsigned short* __restrict__ W2T,
    const float* __restrict__ b2, float* __restrict__ partials, int n, int nTiles) {
  __shared__ float redM[16][8];
  __shared__ float redS[16][8];
  __shared__ float fp_lds[FPL];
  __shared__ float b2_lds[FPL];
  const int wave = threadIdx.x >> 6;
  const int lane = threadIdx.x & 63;
  const int lr = lane & 15;
  const int lg = lane >> 4;
  for (int i = threadIdx.x; i < FPL; i += 512) {
    fp_lds[i] = 0.f;
    b2_lds[i] = b2[i];
  }
  __syncthreads();

  for (int blk = blockIdx.x; blk < nTiles; blk += gridDim.x) {
    const int rowBase = blk * 16;
    short8 a[4];
#pragma unroll
    for (int kt = 0; kt < 4; ++kt)
      a[kt] = *(const short8*)(H + (size_t)(rowBase + lr) * FEAT + kt * 32 + lg * 8);

    f32x4 acc[16];
#pragma unroll
    for (int ct = 0; ct < 16; ++ct) {
      const unsigned short* bp = W2T + (size_t)(wave * 256 + ct * 16 + lr) * FEAT + lg * 8;
      short8 b0 = *(const short8*)(bp);
      short8 b1v = *(const short8*)(bp + 32);
      short8 b2w = *(const short8*)(bp + 64);
      short8 b3v = *(const short8*)(bp + 96);
      f32x4 c = {0.f, 0.f, 0.f, 0.f};
      c = mfma16(a[0], b0, c);
      c = mfma16(a[1], b1v, c);
      c = mfma16(a[2], b2w, c);
      c = mfma16(a[3], b3v, c);
      const float bias = b2_lds[wave * 256 + ct * 16 + lr];
#pragma unroll
      for (int j = 0; j < 4; ++j) c[j] += bias;
      acc[ct] = c;
    }

    // per-row max: over this lane's 16 ct values, then across the 16-lane col group
    float rmax[4];
#pragma unroll
    for (int j = 0; j < 4; ++j) {
      float m = acc[0][j];
#pragma unroll
      for (int ct = 1; ct < 16; ++ct) m = fmaxf(m, acc[ct][j]);
#pragma unroll
      for (int d = 1; d < 16; d <<= 1) m = fmaxf(m, __shfl_xor(m, d, 64));
      rmax[j] = m;
    }
    __syncthreads();  // protects redM/redS reuse across iterations
    if (lr == 0) {
#pragma unroll
      for (int j = 0; j < 4; ++j) redM[lg * 4 + j][wave] = rmax[j];
    }
    __syncthreads();
#pragma unroll
    for (int j = 0; j < 4; ++j) {
      const int r = lg * 4 + j;
      float m = redM[r][0];
#pragma unroll
      for (int w = 1; w < 8; ++w) m = fmaxf(m, redM[r][w]);
      rmax[j] = m;
    }

    // exp + row sums
    float rsum[4];
#pragma unroll
    for (int j = 0; j < 4; ++j) {
      const int row = rowBase + lg * 4 + j;
      const bool valid = row < n;
      float s = 0.f;
#pragma unroll
      for (int ct = 0; ct < 16; ++ct) {
        float e = valid ? __expf(acc[ct][j] - rmax[j]) : 0.f;
        acc[ct][j] = e;
        s += e;
      }
#pragma unroll
      for (int d = 1; d < 16; d <<= 1) s += __shfl_xor(s, d, 64);
      rsum[j] = s;
    }
    if (lr == 0) {
#pragma unroll
      for (int j = 0; j < 4; ++j) redS[lg * 4 + j][wave] = rsum[j];
    }
    __syncthreads();
    float rz[4];
#pragma unroll
    for (int j = 0; j < 4; ++j) {
      const int r = lg * 4 + j;
      float z = 0.f;
#pragma unroll
      for (int w = 0; w < 8; ++w) z += redS[r][w];
      rz[j] = z > 0.f ? 1.0f / z : 0.f;
    }

    // column sums of probs -> fp_lds
#pragma unroll
    for (int ct = 0; ct < 16; ++ct) {
      float s = 0.f;
#pragma unroll
      for (int j = 0; j < 4; ++j) s += acc[ct][j] * rz[j];
      s += __shfl_xor(s, 16, 64);
      s += __shfl_xor(s, 32, 64);
      if (lg == 0) fp_lds[wave * 256 + ct * 16 + lr] += s;
    }
  }
  __syncthreads();
  for (int i = threadIdx.x; i < FPL; i += 512)
    partials[(size_t)blockIdx.x * FPL + i] += fp_lds[i];
}

__global__ void reduce_kernel(const float* __restrict__ partials, float* __restrict__ out, int nPart) {
  int c = blockIdx.x * 256 + threadIdx.x;
  if (c < FPL) {
    float s = 0.f;
    for (int p = 0; p < nPart; ++p) s += partials[(size_t)p * FPL + c];
    out[c] = s;
  }
}

extern "C" void kernel_launch(void* const* d_in, const int* in_sizes, int n_in,
                              void* d_out, int out_size, void* d_ws, size_t ws_size,
                              hipStream_t stream) {
  const float* atoms = (const float*)d_in[0];
  const float* W1 = (const float*)d_in[1];
  const float* b1 = (const float*)d_in[2];
  const float* W2 = (const float*)d_in[3];
  const float* b2 = (const float*)d_in[4];
  const int* esrc = (const int*)d_in[5];
  const int* edst = (const int*)d_in[6];
  const int nAtoms = in_sizes[0] / FEAT;
  const int nEdges = in_sizes[5];
  if (nAtoms <= 0) return;

  const int g1Blocks = (nAtoms + 63) / 64;
  const int nPad = g1Blocks * 64;
  const int g2Tiles = (nAtoms + 15) / 16;
  const int g2Grid = g2Tiles < 1024 ? g2Tiles : 1024;

  size_t off = 0;
  auto alloc = [&](size_t bytes) -> void* {
    void* p = (char*)d_ws + off;
    off += (bytes + 255) & ~(size_t)255;
    return p;
  };
  unsigned short* P = (unsigned short*)alloc((size_t)nPad * FEAT * 2);
  unsigned short* Q = (unsigned short*)alloc((size_t)nPad * FEAT * 2);
  unsigned short* W1T = (unsigned short*)alloc((size_t)FEAT * FEAT * 2);
  unsigned short* W2T = (unsigned short*)alloc((size_t)FEAT * FPL * 2);
  int* counts = (int*)alloc((size_t)nAtoms * 4);
  int* cursor = (int*)alloc((size_t)nAtoms * 4);
  int* rp = (int*)alloc(((size_t)nAtoms + 1) * 4);
  int* col = (int*)alloc((size_t)nEdges * 4);
  float* partials = (float*)alloc((size_t)g2Grid * FPL * 4);

  hipMemsetAsync(counts, 0, (size_t)nAtoms * 4, stream);
  hipMemsetAsync(partials, 0, (size_t)g2Grid * FPL * 4, stream);
  hipMemsetAsync(P + (size_t)nAtoms * FEAT, 0, (size_t)(nPad - nAtoms) * FEAT * 2, stream);
  hipMemsetAsync(Q + (size_t)nAtoms * FEAT, 0, (size_t)(nPad - nAtoms) * FEAT * 2, stream);

  const int n2 = in_sizes[0] / 2;
  cvt_kernel<<<(n2 + 255) / 256, 256, 0, stream>>>(atoms, P, n2);
  cvtT_kernel<<<(FEAT * FEAT + 255) / 256, 256, 0, stream>>>(W1, W1T, FEAT, FEAT);
  cvtT_kernel<<<(FEAT * FPL + 255) / 256, 256, 0, stream>>>(W2, W2T, FEAT, FPL);
  count_kernel<<<(nEdges + 255) / 256, 256, 0, stream>>>(edst, counts, nEdges);
  scan_kernel<<<1, 1024, 0, stream>>>(counts, rp, nAtoms);
  copy_kernel<<<(nAtoms + 255) / 256, 256, 0, stream>>>(rp, cursor, nAtoms);
  fill_kernel<<<(nEdges + 255) / 256, 256, 0, stream>>>(esrc, edst, cursor, col, nEdges);

  unsigned short* x = P;
  unsigned short* y = Q;
  for (int step = 0; step < 3; ++step) {
    gather_kernel<<<(nAtoms + 3) / 4, 256, 0, stream>>>(x, rp, col, y, nAtoms);
    gemm1_kernel<<<g1Blocks, 256, 0, stream>>>(y, W1T, b1, y, nAtoms);
    gemm2_kernel<<<g2Grid, 512, 0, stream>>>(y, W2T, b2, partials, nAtoms, g2Tiles);
    unsigned short* t = x; x = y; y = t;
  }
  reduce_kernel<<<(FPL + 255) / 256, 256, 0, stream>>>(partials, (float*)d_out, g2Grid);
}

// Round 4
// 1181.139 us; speedup vs baseline: 1.4163x; 1.3541x over previous
//
#include <hip/hip_runtime.h>

typedef short short8 __attribute__((ext_vector_type(8)));
typedef __bf16 bf16x8 __attribute__((ext_vector_type(8)));
typedef float f32x4 __attribute__((ext_vector_type(4)));

#define FEAT 128
#define FPL 2048

__device__ __forceinline__ float b2f(unsigned int u) {
  union { unsigned int u; float f; } c; c.u = u << 16; return c.f;
}
__device__ __forceinline__ unsigned short f2b(float f) {
  union { float f; unsigned int u; } c; c.f = f;
  unsigned int r = c.u + 0x7fffu + ((c.u >> 16) & 1u);
  return (unsigned short)(r >> 16);
}
__device__ __forceinline__ f32x4 mfma16(short8 a, short8 b, f32x4 c) {
  return __builtin_amdgcn_mfma_f32_16x16x32_bf16(
      __builtin_bit_cast(bf16x8, a), __builtin_bit_cast(bf16x8, b), c, 0, 0, 0);
}

// ---- conversion kernels ----
__global__ void cvt_kernel(const float* __restrict__ in, unsigned short* __restrict__ out, int n2) {
  int i = blockIdx.x * 256 + threadIdx.x;
  if (i < n2) {
    float2 v = ((const float2*)in)[i];
    unsigned int lo = f2b(v.x), hi = f2b(v.y);
    ((unsigned int*)out)[i] = lo | (hi << 16);
  }
}

// W[K][N] (row-major) -> WT[N][K] bf16
__global__ void cvtT_kernel(const float* __restrict__ W, unsigned short* __restrict__ WT, int K, int N) {
  int i = blockIdx.x * 256 + threadIdx.x;
  if (i < K * N) {
    int k = i / N, c = i - k * N;
    WT[(size_t)c * K + k] = f2b(W[i]);
  }
}

// ---- CSR build ----
__global__ void count_kernel(const int* __restrict__ dst, int* __restrict__ cnt, int n) {
  int i = blockIdx.x * 256 + threadIdx.x;
  if (i < n) atomicAdd(&cnt[dst[i]], 1);
}

__global__ __launch_bounds__(1024) void scan_kernel(const int* __restrict__ cnt, int* __restrict__ rp, int n) {
  __shared__ int sd[1024];
  __shared__ int carry;
  if (threadIdx.x == 0) carry = 0;
  __syncthreads();
  for (int base = 0; base < n; base += 1024) {
    int i = base + (int)threadIdx.x;
    int v = (i < n) ? cnt[i] : 0;
    sd[threadIdx.x] = v;
    __syncthreads();
    int sum = v;
    for (int off = 1; off < 1024; off <<= 1) {
      int t = (threadIdx.x >= (unsigned)off) ? sd[threadIdx.x - off] : 0;
      __syncthreads();
      sum += t;
      sd[threadIdx.x] = sum;
      __syncthreads();
    }
    if (i < n) rp[i] = carry + sum - v;  // exclusive
    __syncthreads();
    if (threadIdx.x == 1023) carry += sum;
    __syncthreads();
  }
  if (threadIdx.x == 0) rp[n] = carry;
}

__global__ void copy_kernel(const int* __restrict__ a, int* __restrict__ b, int n) {
  int i = blockIdx.x * 256 + threadIdx.x;
  if (i < n) b[i] = a[i];
}

__global__ void fill_kernel(const int* __restrict__ src, const int* __restrict__ dst,
                            int* __restrict__ cursor, int* __restrict__ col, int n) {
  int i = blockIdx.x * 256 + threadIdx.x;
  if (i < n) {
    int p = atomicAdd(&cursor[dst[i]], 1);
    col[p] = src[i];
  }
}

// ---- neighbor gather: agg[i] = x[i] + sum_{j in N(i)} x[j], bf16 in/out, fp32 accum ----
__global__ __launch_bounds__(256) void gather_kernel(const unsigned short* __restrict__ x,
    const int* __restrict__ rp, const int* __restrict__ col,
    unsigned short* __restrict__ agg, int n) {
  int wid = (blockIdx.x * 256 + threadIdx.x) >> 6;
  int lane = threadIdx.x & 63;
  if (wid >= n) return;
  const unsigned int* xw = (const unsigned int*)x;
  unsigned int s = xw[(size_t)wid * 64 + lane];
  float ax = b2f(s & 0xffffu), ay = b2f(s >> 16);
  int beg = rp[wid], end = rp[wid + 1];
  int j = beg;
  for (; j + 4 <= end; j += 4) {
    int c0 = col[j], c1 = col[j + 1], c2 = col[j + 2], c3 = col[j + 3];
    unsigned int v0 = xw[(size_t)c0 * 64 + lane];
    unsigned int v1 = xw[(size_t)c1 * 64 + lane];
    unsigned int v2 = xw[(size_t)c2 * 64 + lane];
    unsigned int v3 = xw[(size_t)c3 * 64 + lane];
    ax += b2f(v0 & 0xffffu) + b2f(v1 & 0xffffu) + b2f(v2 & 0xffffu) + b2f(v3 & 0xffffu);
    ay += b2f(v0 >> 16) + b2f(v1 >> 16) + b2f(v2 >> 16) + b2f(v3 >> 16);
  }
  for (; j < end; ++j) {
    unsigned int v = xw[(size_t)col[j] * 64 + lane];
    ax += b2f(v & 0xffffu);
    ay += b2f(v >> 16);
  }
  ((unsigned int*)agg)[(size_t)wid * 64 + lane] = (unsigned int)f2b(ax) | ((unsigned int)f2b(ay) << 16);
}

// ---- GEMM1: H = relu(A @ W1 + b1), [n,128]x[128,128], bf16 in/out ----
__global__ __launch_bounds__(256) void gemm1_kernel(
    const unsigned short* __restrict__ A, const unsigned short* __restrict__ W1T,
    const float* __restrict__ b1, unsigned short* __restrict__ H, int n) {
  const int wave = threadIdx.x >> 6;
  const int lane = threadIdx.x & 63;
  const int lr = lane & 15, lg = lane >> 4;
  const int rowBase = blockIdx.x * 64 + wave * 16;
  short8 a[4];
#pragma unroll
  for (int kt = 0; kt < 4; ++kt)
    a[kt] = *(const short8*)(A + (size_t)(rowBase + lr) * FEAT + kt * 32 + lg * 8);
  f32x4 acc[8];
#pragma unroll
  for (int ct = 0; ct < 8; ++ct) {
    const unsigned short* bp = W1T + (size_t)(ct * 16 + lr) * FEAT + lg * 8;
    f32x4 c = {0.f, 0.f, 0.f, 0.f};
    c = mfma16(a[0], *(const short8*)(bp), c);
    c = mfma16(a[1], *(const short8*)(bp + 32), c);
    c = mfma16(a[2], *(const short8*)(bp + 64), c);
    c = mfma16(a[3], *(const short8*)(bp + 96), c);
    acc[ct] = c;
  }
#pragma unroll
  for (int ct = 0; ct < 8; ++ct) {
    const int c = ct * 16 + lr;
    const float bias = b1[c];
#pragma unroll
    for (int j = 0; j < 4; ++j) {
      const int row = rowBase + lg * 4 + j;
      if (row < n) {
        float v = acc[ct][j] + bias;
        H[(size_t)row * FEAT + c] = f2b(v > 0.f ? v : 0.f);
      }
    }
  }
}

// ---- GEMM2 fused: logits = H @ W2 + b2; softmax rows; fp_partial += colsum(probs) ----
// 512 threads = 8 waves; tile = 16 rows x 2048 cols; wave w owns cols [256w,256w+256).
// Logits live in LDS (128 KiB), NOT registers: rounds 1-3 proved the register
// version spills ~700 MB/dispatch of scratch to HBM at the compiler's 128-VGPR cap.
// Phase 1: MFMA -> LDS (lane-local max tracked on the fly). Phase 2: exp + row
// sums (exp written back). Phase 3: column sums of probs -> fp_lds.
// Per-thread live set ~90 VGPR -> no spill. 1 block/CU (LDS-bound), persistent.
__global__ __launch_bounds__(512) void gemm2_kernel(
    const unsigned short* __restrict__ H, const unsigned short* __restrict__ W2T,
    const float* __restrict__ b2, float* __restrict__ partials, int n, int nTiles) {
  __shared__ f32x4 logits4[8 * 16 * 4 * 16];  // [wave][ct][lg][lr] = 128 KiB
  __shared__ float redM[16][8];
  __shared__ float redS[16][8];
  __shared__ float fp_lds[FPL];
  const int wave = threadIdx.x >> 6;
  const int lane = threadIdx.x & 63;
  const int lr = lane & 15;
  const int lg = lane >> 4;
  const int lbase = wave * 1024 + lg * 16 + lr;  // f32x4 index; + ct*64 per ct
  for (int i = threadIdx.x; i < FPL; i += 512) fp_lds[i] = 0.f;
  float b2v[16];
#pragma unroll
  for (int ct = 0; ct < 16; ++ct) b2v[ct] = b2[wave * 256 + ct * 16 + lr];
  __syncthreads();

  for (int blk = blockIdx.x; blk < nTiles; blk += gridDim.x) {
    const int rowBase = blk * 16;
    short8 a[4];
#pragma unroll
    for (int kt = 0; kt < 4; ++kt)
      a[kt] = *(const short8*)(H + (size_t)(rowBase + lr) * FEAT + kt * 32 + lg * 8);

    // Phase 1: MFMA -> LDS, tracking lane-local per-j max
    float rmax[4] = {-1e30f, -1e30f, -1e30f, -1e30f};
#pragma unroll
    for (int ct = 0; ct < 16; ++ct) {
      const unsigned short* bp = W2T + (size_t)(wave * 256 + ct * 16 + lr) * FEAT + lg * 8;
      f32x4 c = {0.f, 0.f, 0.f, 0.f};
      c = mfma16(a[0], *(const short8*)(bp), c);
      c = mfma16(a[1], *(const short8*)(bp + 32), c);
      c = mfma16(a[2], *(const short8*)(bp + 64), c);
      c = mfma16(a[3], *(const short8*)(bp + 96), c);
      const float bias = b2v[ct];
#pragma unroll
      for (int j = 0; j < 4; ++j) {
        c[j] += bias;
        rmax[j] = fmaxf(rmax[j], c[j]);
      }
      logits4[lbase + ct * 64] = c;
    }

    // row max: across the 16-lane col group, then across waves
#pragma unroll
    for (int j = 0; j < 4; ++j) {
#pragma unroll
      for (int d = 1; d < 16; d <<= 1) rmax[j] = fmaxf(rmax[j], __shfl_xor(rmax[j], d, 64));
    }
    __syncthreads();  // protects redM/redS reuse across iterations
    if (lr == 0) {
#pragma unroll
      for (int j = 0; j < 4; ++j) redM[lg * 4 + j][wave] = rmax[j];
    }
    __syncthreads();
#pragma unroll
    for (int j = 0; j < 4; ++j) {
      const int r = lg * 4 + j;
      float m = redM[r][0];
#pragma unroll
      for (int w = 1; w < 8; ++w) m = fmaxf(m, redM[r][w]);
      rmax[j] = m;
    }

    // Phase 2: exp (written back to LDS) + row sums
    float rsum[4] = {0.f, 0.f, 0.f, 0.f};
    {
      const int row0 = rowBase + lg * 4;
#pragma unroll
      for (int ct = 0; ct < 16; ++ct) {
        f32x4 v = logits4[lbase + ct * 64];
#pragma unroll
        for (int j = 0; j < 4; ++j) {
          float e = (row0 + j < n) ? __expf(v[j] - rmax[j]) : 0.f;
          v[j] = e;
          rsum[j] += e;
        }
        logits4[lbase + ct * 64] = v;
      }
    }
#pragma unroll
    for (int j = 0; j < 4; ++j) {
#pragma unroll
      for (int d = 1; d < 16; d <<= 1) rsum[j] += __shfl_xor(rsum[j], d, 64);
    }
    if (lr == 0) {
#pragma unroll
      for (int j = 0; j < 4; ++j) redS[lg * 4 + j][wave] = rsum[j];
    }
    __syncthreads();
    float rz[4];
#pragma unroll
    for (int j = 0; j < 4; ++j) {
      const int r = lg * 4 + j;
      float z = 0.f;
#pragma unroll
      for (int w = 0; w < 8; ++w) z += redS[r][w];
      rz[j] = z > 0.f ? 1.0f / z : 0.f;
    }

    // Phase 3: column sums of probs -> fp_lds
#pragma unroll
    for (int ct = 0; ct < 16; ++ct) {
      f32x4 v = logits4[lbase + ct * 64];
      float s = v[0] * rz[0] + v[1] * rz[1] + v[2] * rz[2] + v[3] * rz[3];
      s += __shfl_xor(s, 16, 64);
      s += __shfl_xor(s, 32, 64);
      if (lg == 0) fp_lds[wave * 256 + ct * 16 + lr] += s;
    }
  }
  __syncthreads();
  for (int i = threadIdx.x; i < FPL; i += 512)
    partials[(size_t)blockIdx.x * FPL + i] += fp_lds[i];
}

__global__ void reduce_kernel(const float* __restrict__ partials, float* __restrict__ out, int nPart) {
  int c = blockIdx.x * 256 + threadIdx.x;
  if (c < FPL) {
    float s = 0.f;
    for (int p = 0; p < nPart; ++p) s += partials[(size_t)p * FPL + c];
    out[c] = s;
  }
}

extern "C" void kernel_launch(void* const* d_in, const int* in_sizes, int n_in,
                              void* d_out, int out_size, void* d_ws, size_t ws_size,
                              hipStream_t stream) {
  const float* atoms = (const float*)d_in[0];
  const float* W1 = (const float*)d_in[1];
  const float* b1 = (const float*)d_in[2];
  const float* W2 = (const float*)d_in[3];
  const float* b2 = (const float*)d_in[4];
  const int* esrc = (const int*)d_in[5];
  const int* edst = (const int*)d_in[6];
  const int nAtoms = in_sizes[0] / FEAT;
  const int nEdges = in_sizes[5];
  if (nAtoms <= 0) return;

  const int g1Blocks = (nAtoms + 63) / 64;
  const int nPad = g1Blocks * 64;
  const int g2Tiles = (nAtoms + 15) / 16;
  const int g2Grid = g2Tiles < 256 ? g2Tiles : 256;  // persistent, 1 block/CU

  size_t off = 0;
  auto alloc = [&](size_t bytes) -> void* {
    void* p = (char*)d_ws + off;
    off += (bytes + 255) & ~(size_t)255;
    return p;
  };
  unsigned short* P = (unsigned short*)alloc((size_t)nPad * FEAT * 2);
  unsigned short* Q = (unsigned short*)alloc((size_t)nPad * FEAT * 2);
  unsigned short* W1T = (unsigned short*)alloc((size_t)FEAT * FEAT * 2);
  unsigned short* W2T = (unsigned short*)alloc((size_t)FEAT * FPL * 2);
  int* counts = (int*)alloc((size_t)nAtoms * 4);
  int* cursor = (int*)alloc((size_t)nAtoms * 4);
  int* rp = (int*)alloc(((size_t)nAtoms + 1) * 4);
  int* col = (int*)alloc((size_t)nEdges * 4);
  float* partials = (float*)alloc((size_t)g2Grid * FPL * 4);

  hipMemsetAsync(counts, 0, (size_t)nAtoms * 4, stream);
  hipMemsetAsync(partials, 0, (size_t)g2Grid * FPL * 4, stream);
  hipMemsetAsync(P + (size_t)nAtoms * FEAT, 0, (size_t)(nPad - nAtoms) * FEAT * 2, stream);
  hipMemsetAsync(Q + (size_t)nAtoms * FEAT, 0, (size_t)(nPad - nAtoms) * FEAT * 2, stream);

  const int n2 = in_sizes[0] / 2;
  cvt_kernel<<<(n2 + 255) / 256, 256, 0, stream>>>(atoms, P, n2);
  cvtT_kernel<<<(FEAT * FEAT + 255) / 256, 256, 0, stream>>>(W1, W1T, FEAT, FEAT);
  cvtT_kernel<<<(FEAT * FPL + 255) / 256, 256, 0, stream>>>(W2, W2T, FEAT, FPL);
  count_kernel<<<(nEdges + 255) / 256, 256, 0, stream>>>(edst, counts, nEdges);
  scan_kernel<<<1, 1024, 0, stream>>>(counts, rp, nAtoms);
  copy_kernel<<<(nAtoms + 255) / 256, 256, 0, stream>>>(rp, cursor, nAtoms);
  fill_kernel<<<(nEdges + 255) / 256, 256, 0, stream>>>(esrc, edst, cursor, col, nEdges);

  unsigned short* x = P;
  unsigned short* y = Q;
  for (int step = 0; step < 3; ++step) {
    gather_kernel<<<(nAtoms + 3) / 4, 256, 0, stream>>>(x, rp, col, y, nAtoms);
    gemm1_kernel<<<g1Blocks, 256, 0, stream>>>(y, W1T, b1, y, nAtoms);
    gemm2_kernel<<<g2Grid, 512, 0, stream>>>(y, W2T, b2, partials, nAtoms, g2Tiles);
    unsigned short* t = x; x = y; y = t;
  }
  reduce_kernel<<<(FPL + 255) / 256, 256, 0, stream>>>(partials, (float*)d_out, g2Grid);
}